// Round 1
// baseline (5620.528 us; speedup 1.0000x reference)
//
#include <hip/hip_runtime.h>

#define N_NODES 50000
#define N_EDGES 1600000
#define IN_F    512
#define OUT_F   256

// ---------------------------------------------------------------------------
// Kernel 1: support[M][N] = features[M][K] @ weight[K][N]   (fp32, vector ALU)
// BM=64 BN=64 BK=16, 256 threads, 4x4 accumulators per thread.
// ---------------------------------------------------------------------------
__global__ __launch_bounds__(256) void gemm_kernel(const float* __restrict__ A,
                                                   const float* __restrict__ B,
                                                   float* __restrict__ C) {
    __shared__ float As[16][64];   // As[k][m]
    __shared__ float Bs[16][64];   // Bs[k][n]

    const int tid = threadIdx.x;
    const int tx  = tid & 15;          // n-dim, 0..15
    const int ty  = tid >> 4;          // m-dim, 0..15
    const int n0  = blockIdx.x * 64;
    const int m0  = blockIdx.y * 64;

    // staging index precompute
    const int a_row = tid >> 2;          // 0..63  (m within tile)
    const int a_kq  = (tid & 3) * 4;     // 0,4,8,12 (k within tile)
    const int b_krow = tid >> 4;         // 0..15  (k within tile)
    const int b_nq   = (tid & 15) * 4;   // n within tile

    float acc[4][4];
#pragma unroll
    for (int i = 0; i < 4; ++i)
#pragma unroll
        for (int j = 0; j < 4; ++j) acc[i][j] = 0.f;

    for (int k0 = 0; k0 < IN_F; k0 += 16) {
        // stage A tile (64 rows x 16 k), transposed into As[k][m]
        {
            const int m = m0 + a_row;
            float4 av = make_float4(0.f, 0.f, 0.f, 0.f);
            if (m < N_NODES)
                av = *(const float4*)(A + (size_t)m * IN_F + k0 + a_kq);
            As[a_kq + 0][a_row] = av.x;
            As[a_kq + 1][a_row] = av.y;
            As[a_kq + 2][a_row] = av.z;
            As[a_kq + 3][a_row] = av.w;
        }
        // stage B tile (16 k x 64 n)
        {
            const float4 bv = *(const float4*)(B + (size_t)(k0 + b_krow) * OUT_F + n0 + b_nq);
            *(float4*)&Bs[b_krow][b_nq] = bv;
        }
        __syncthreads();

#pragma unroll
        for (int kk = 0; kk < 16; ++kk) {
            float a[4], b[4];
#pragma unroll
            for (int i = 0; i < 4; ++i) a[i] = As[kk][ty * 4 + i];
#pragma unroll
            for (int j = 0; j < 4; ++j) b[j] = Bs[kk][tx * 4 + j];
#pragma unroll
            for (int i = 0; i < 4; ++i)
#pragma unroll
                for (int j = 0; j < 4; ++j) acc[i][j] += a[i] * b[j];
        }
        __syncthreads();
    }

    // write 4x4 per thread, float4 rows
#pragma unroll
    for (int i = 0; i < 4; ++i) {
        const int m = m0 + ty * 4 + i;
        if (m < N_NODES) {
            float4 v = make_float4(acc[i][0], acc[i][1], acc[i][2], acc[i][3]);
            *(float4*)(C + (size_t)m * OUT_F + n0 + tx * 4) = v;
        }
    }
}

// ---------------------------------------------------------------------------
// Kernel 2: zero the output accumulator (harness poisons d_out with 0xAA)
// ---------------------------------------------------------------------------
__global__ __launch_bounds__(256) void zero_kernel(float4* __restrict__ out, int n4) {
    int i = blockIdx.x * 256 + threadIdx.x;
    if (i < n4) out[i] = make_float4(0.f, 0.f, 0.f, 0.f);
}

// ---------------------------------------------------------------------------
// Kernel 3: COO scatter — one wave (64 lanes) per edge, float4 per lane,
// 4 scalar fp32 atomics into out[row].
// ---------------------------------------------------------------------------
__global__ __launch_bounds__(256) void scatter_kernel(const float4* __restrict__ support,
                                                      const float* __restrict__ vals,
                                                      const int* __restrict__ rows,
                                                      const int* __restrict__ cols,
                                                      float* __restrict__ out) {
    const int t    = blockIdx.x * 256 + threadIdx.x;
    const int e    = t >> 6;        // wave-uniform: one edge per wave
    const int lane = t & 63;
    if (e >= N_EDGES) return;
    const int   r = rows[e];
    const int   c = cols[e];
    const float v = vals[e];
    const float4 s = support[(size_t)c * (OUT_F / 4) + lane];
    float* op = out + (size_t)r * OUT_F + lane * 4;
    atomicAdd(op + 0, v * s.x);
    atomicAdd(op + 1, v * s.y);
    atomicAdd(op + 2, v * s.z);
    atomicAdd(op + 3, v * s.w);
}

// ---------------------------------------------------------------------------
// Kernel 4: in-place ReLU
// ---------------------------------------------------------------------------
__global__ __launch_bounds__(256) void relu_kernel(float4* __restrict__ out, int n4) {
    int i = blockIdx.x * 256 + threadIdx.x;
    if (i < n4) {
        float4 v = out[i];
        v.x = fmaxf(v.x, 0.f);
        v.y = fmaxf(v.y, 0.f);
        v.z = fmaxf(v.z, 0.f);
        v.w = fmaxf(v.w, 0.f);
        out[i] = v;
    }
}

extern "C" void kernel_launch(void* const* d_in, const int* in_sizes, int n_in,
                              void* d_out, int out_size, void* d_ws, size_t ws_size,
                              hipStream_t stream) {
    const float* features = (const float*)d_in[0];   // [50000, 512]
    const float* weight   = (const float*)d_in[1];   // [512, 256]
    const float* edge_vals = (const float*)d_in[2];  // [1.6M]
    const int*   edge_rows = (const int*)d_in[3];
    const int*   edge_cols = (const int*)d_in[4];
    float* out = (float*)d_out;                      // [50000, 256]

    float* support = (float*)d_ws;                   // 50000*256*4 = 51.2 MB

    // 1) zero output accumulator
    const int n4 = (N_NODES * OUT_F) / 4;            // 3.2M float4
    zero_kernel<<<(n4 + 255) / 256, 256, 0, stream>>>((float4*)out, n4);

    // 2) dense GEMM: support = features @ weight
    dim3 ggrid(OUT_F / 64, (N_NODES + 63) / 64);     // (4, 782)
    gemm_kernel<<<ggrid, 256, 0, stream>>>(features, weight, support);

    // 3) COO scatter with atomics: out[r] += val * support[c]
    const long long threads = (long long)N_EDGES * 64;
    scatter_kernel<<<(int)(threads / 256), 256, 0, stream>>>(
        (const float4*)support, edge_vals, edge_rows, edge_cols, out);

    // 4) ReLU in place
    relu_kernel<<<(n4 + 255) / 256, 256, 0, stream>>>((float4*)out, n4);
}

// Round 3
// 713.682 us; speedup vs baseline: 7.8754x; 7.8754x over previous
//
#include <hip/hip_runtime.h>

#define N_NODES 50000
#define N_EDGES 1600000
#define IN_F    512
#define OUT_F   256

#define SCAN_B  256
#define N_SCAN_BLOCKS ((N_NODES + SCAN_B - 1) / SCAN_B)   // 196

// ---------------------------------------------------------------------------
// Kernel 1: support[M][N] = features[M][K] @ weight[K][N]   (fp32, vector ALU)
// ---------------------------------------------------------------------------
__global__ __launch_bounds__(256) void gemm_kernel(const float* __restrict__ A,
                                                   const float* __restrict__ B,
                                                   float* __restrict__ C) {
    __shared__ float As[16][64];   // As[k][m]
    __shared__ float Bs[16][64];   // Bs[k][n]

    const int tid = threadIdx.x;
    const int tx  = tid & 15;
    const int ty  = tid >> 4;
    const int n0  = blockIdx.x * 64;
    const int m0  = blockIdx.y * 64;

    const int a_row = tid >> 2;
    const int a_kq  = (tid & 3) * 4;
    const int b_krow = tid >> 4;
    const int b_nq   = (tid & 15) * 4;

    float acc[4][4];
#pragma unroll
    for (int i = 0; i < 4; ++i)
#pragma unroll
        for (int j = 0; j < 4; ++j) acc[i][j] = 0.f;

    for (int k0 = 0; k0 < IN_F; k0 += 16) {
        {
            const int m = m0 + a_row;
            float4 av = make_float4(0.f, 0.f, 0.f, 0.f);
            if (m < N_NODES)
                av = *(const float4*)(A + (size_t)m * IN_F + k0 + a_kq);
            As[a_kq + 0][a_row] = av.x;
            As[a_kq + 1][a_row] = av.y;
            As[a_kq + 2][a_row] = av.z;
            As[a_kq + 3][a_row] = av.w;
        }
        {
            const float4 bv = *(const float4*)(B + (size_t)(k0 + b_krow) * OUT_F + n0 + b_nq);
            *(float4*)&Bs[b_krow][b_nq] = bv;
        }
        __syncthreads();

#pragma unroll
        for (int kk = 0; kk < 16; ++kk) {
            float a[4], b[4];
#pragma unroll
            for (int i = 0; i < 4; ++i) a[i] = As[kk][ty * 4 + i];
#pragma unroll
            for (int j = 0; j < 4; ++j) b[j] = Bs[kk][tx * 4 + j];
#pragma unroll
            for (int i = 0; i < 4; ++i)
#pragma unroll
                for (int j = 0; j < 4; ++j) acc[i][j] += a[i] * b[j];
        }
        __syncthreads();
    }

#pragma unroll
    for (int i = 0; i < 4; ++i) {
        const int m = m0 + ty * 4 + i;
        if (m < N_NODES) {
            float4 v = make_float4(acc[i][0], acc[i][1], acc[i][2], acc[i][3]);
            *(float4*)(C + (size_t)m * OUT_F + n0 + tx * 4) = v;
        }
    }
}

// ---------------------------------------------------------------------------
// CSR build: zero counts -> histogram -> hierarchical exclusive scan -> fill
// ---------------------------------------------------------------------------
__global__ __launch_bounds__(256) void zero_counts_kernel(int* __restrict__ counts) {
    int i = blockIdx.x * 256 + threadIdx.x;
    if (i < N_NODES) counts[i] = 0;
}

__global__ __launch_bounds__(256) void hist_kernel(const int* __restrict__ rows,
                                                   int* __restrict__ counts) {
    int e = blockIdx.x * 256 + threadIdx.x;
    if (e < N_EDGES) atomicAdd(&counts[rows[e]], 1);
}

// per-block inclusive scan -> exclusive out + block total
__global__ __launch_bounds__(SCAN_B) void scan1_kernel(const int* __restrict__ counts,
                                                       int* __restrict__ excl,
                                                       int* __restrict__ blockSums) {
    __shared__ int s[SCAN_B];
    const int tid = threadIdx.x;
    const int i   = blockIdx.x * SCAN_B + tid;
    const int c   = (i < N_NODES) ? counts[i] : 0;
    s[tid] = c;
#pragma unroll
    for (int off = 1; off < SCAN_B; off <<= 1) {
        __syncthreads();
        int t = (tid >= off) ? s[tid - off] : 0;
        __syncthreads();
        s[tid] += t;
    }
    __syncthreads();
    if (i < N_NODES) excl[i] = s[tid] - c;
    if (tid == SCAN_B - 1) blockSums[blockIdx.x] = s[tid];
}

// exclusive scan of block sums (N_SCAN_BLOCKS <= 256), single block
__global__ __launch_bounds__(SCAN_B) void scan2_kernel(int* __restrict__ blockSums,
                                                       int* __restrict__ blockOffs) {
    __shared__ int s[SCAN_B];
    const int tid = threadIdx.x;
    const int c = (tid < N_SCAN_BLOCKS) ? blockSums[tid] : 0;
    s[tid] = c;
#pragma unroll
    for (int off = 1; off < SCAN_B; off <<= 1) {
        __syncthreads();
        int t = (tid >= off) ? s[tid - off] : 0;
        __syncthreads();
        s[tid] += t;
    }
    __syncthreads();
    if (tid < N_SCAN_BLOCKS) blockOffs[tid] = s[tid] - c;
}

// add block offsets; also init cursor = excl
__global__ __launch_bounds__(SCAN_B) void scan3_kernel(int* __restrict__ excl,
                                                       const int* __restrict__ blockOffs,
                                                       int* __restrict__ cursor) {
    const int i = blockIdx.x * SCAN_B + threadIdx.x;
    if (i < N_NODES) {
        const int v = excl[i] + blockOffs[blockIdx.x];
        excl[i] = v;
        cursor[i] = v;
    }
}

__global__ __launch_bounds__(256) void fill_kernel(const int* __restrict__ rows,
                                                   const int* __restrict__ cols,
                                                   const float* __restrict__ vals,
                                                   int* __restrict__ cursor,
                                                   int* __restrict__ sorted_col,
                                                   float* __restrict__ sorted_val) {
    int e = blockIdx.x * 256 + threadIdx.x;
    if (e < N_EDGES) {
        const int pos = atomicAdd(&cursor[rows[e]], 1);
        sorted_col[pos] = cols[e];
        sorted_val[pos] = vals[e];
    }
}

// ---------------------------------------------------------------------------
// Gather: one wave per output row. lane holds float4 (OUT_F/4 = 64 = lanes).
// out[r] = relu( sum_e val_e * support[col_e] )   — no atomics, fused ReLU.
// ---------------------------------------------------------------------------
__global__ __launch_bounds__(256) void gather_kernel(const float4* __restrict__ support,
                                                     const int* __restrict__ excl,
                                                     const int* __restrict__ counts,
                                                     const int* __restrict__ sorted_col,
                                                     const float* __restrict__ sorted_val,
                                                     float4* __restrict__ out) {
    const int tid  = threadIdx.x;
    const int row  = blockIdx.x * 4 + (tid >> 6);   // one wave per row
    const int lane = tid & 63;
    if (row >= N_NODES) return;

    const int start = excl[row];
    const int end   = start + counts[row];

    float4 acc = make_float4(0.f, 0.f, 0.f, 0.f);
    int e = start;
    for (; e + 1 < end; e += 2) {
        const int   c0 = sorted_col[e];
        const int   c1 = sorted_col[e + 1];
        const float v0 = sorted_val[e];
        const float v1 = sorted_val[e + 1];
        const float4 s0 = support[(size_t)c0 * 64 + lane];
        const float4 s1 = support[(size_t)c1 * 64 + lane];
        acc.x += v0 * s0.x; acc.y += v0 * s0.y; acc.z += v0 * s0.z; acc.w += v0 * s0.w;
        acc.x += v1 * s1.x; acc.y += v1 * s1.y; acc.z += v1 * s1.z; acc.w += v1 * s1.w;
    }
    if (e < end) {
        const int   c0 = sorted_col[e];
        const float v0 = sorted_val[e];
        const float4 s0 = support[(size_t)c0 * 64 + lane];
        acc.x += v0 * s0.x; acc.y += v0 * s0.y; acc.z += v0 * s0.z; acc.w += v0 * s0.w;
    }

    acc.x = fmaxf(acc.x, 0.f);
    acc.y = fmaxf(acc.y, 0.f);
    acc.z = fmaxf(acc.z, 0.f);
    acc.w = fmaxf(acc.w, 0.f);
    out[(size_t)row * 64 + lane] = acc;
}

extern "C" void kernel_launch(void* const* d_in, const int* in_sizes, int n_in,
                              void* d_out, int out_size, void* d_ws, size_t ws_size,
                              hipStream_t stream) {
    const float* features  = (const float*)d_in[0];   // [50000, 512]
    const float* weight    = (const float*)d_in[1];   // [512, 256]
    const float* edge_vals = (const float*)d_in[2];   // [1.6M]
    const int*   edge_rows = (const int*)d_in[3];
    const int*   edge_cols = (const int*)d_in[4];
    float* out = (float*)d_out;                       // [50000, 256]

    // workspace layout
    float* support    = (float*)d_ws;                          // 12.8M floats (51.2 MB)
    int*   counts     = (int*)(support + (size_t)N_NODES * OUT_F);  // 50000
    int*   excl       = counts + N_NODES;                      // 50000
    int*   cursor     = excl + N_NODES;                        // 50000
    int*   blockSums  = cursor + N_NODES;                      // 256
    int*   blockOffs  = blockSums + 256;                       // 256
    int*   sorted_col = blockOffs + 256;                       // 1.6M
    float* sorted_val = (float*)(sorted_col + N_EDGES);        // 1.6M

    // 1) dense GEMM: support = features @ weight
    dim3 ggrid(OUT_F / 64, (N_NODES + 63) / 64);
    gemm_kernel<<<ggrid, 256, 0, stream>>>(features, weight, support);

    // 2) CSR build (counting sort by destination row)
    zero_counts_kernel<<<(N_NODES + 255) / 256, 256, 0, stream>>>(counts);
    hist_kernel<<<(N_EDGES + 255) / 256, 256, 0, stream>>>(edge_rows, counts);
    scan1_kernel<<<N_SCAN_BLOCKS, SCAN_B, 0, stream>>>(counts, excl, blockSums);
    scan2_kernel<<<1, SCAN_B, 0, stream>>>(blockSums, blockOffs);
    scan3_kernel<<<N_SCAN_BLOCKS, SCAN_B, 0, stream>>>(excl, blockOffs, cursor);
    fill_kernel<<<(N_EDGES + 255) / 256, 256, 0, stream>>>(
        edge_rows, edge_cols, edge_vals, cursor, sorted_col, sorted_val);

    // 3) gather + fused ReLU (one wave per row, no atomics)
    gather_kernel<<<(N_NODES + 3) / 4, 256, 0, stream>>>(
        (const float4*)support, excl, counts, sorted_col, sorted_val, (float4*)out);
}

// Round 4
// 612.593 us; speedup vs baseline: 9.1750x; 1.1650x over previous
//
#include <hip/hip_runtime.h>

#define N_NODES 50000
#define N_EDGES 1600000
#define IN_F    512
#define OUT_F   256

#define SCAN_B  256
#define N_SCAN_BLOCKS ((N_NODES + SCAN_B - 1) / SCAN_B)   // 196

typedef __attribute__((ext_vector_type(8))) short bf16x8;
typedef __attribute__((ext_vector_type(4))) float f32x4;

__device__ __forceinline__ short bf16rne(float f) {
    unsigned u = __builtin_bit_cast(unsigned, f);
    u += 0x7fffu + ((u >> 16) & 1u);          // round-to-nearest-even
    return (short)(u >> 16);
}

// ---------------------------------------------------------------------------
// Kernel 0: Wt[n][k] = bf16(W[k][n])  — transpose + convert weight (512x256)
// ---------------------------------------------------------------------------
__global__ __launch_bounds__(256) void wt_kernel(const float* __restrict__ W,
                                                 short* __restrict__ Wt) {
    int idx = blockIdx.x * 256 + threadIdx.x;       // 131072 total
    if (idx < IN_F * OUT_F) {
        int n = idx >> 9;          // /512
        int k = idx & 511;
        Wt[idx] = bf16rne(W[(size_t)k * OUT_F + n]);
    }
}

// ---------------------------------------------------------------------------
// Kernel 1: support = features @ weight via bf16 MFMA.
// BM=64, BN=256 (full N -> A read once), BK=32. 256 threads = 4 waves,
// wave w owns cols [w*64, w*64+64); 4x4 grid of 16x16x32 MFMA frags.
// A layout in LDS: As[m][k] row-major, stride 40 bf16 (pad 8, 80B rows).
// B layout in LDS: Bs[n][k] (transposed weight), stride 40 bf16.
// A-frag: lane holds A[m=lane&15][k=(lane>>4)*8+j]  (16B contiguous)
// B-frag: lane holds B[k=(lane>>4)*8+j][n=lane&15]  -> Bs[n][k] 16B contiguous
// C/D:    col=lane&15, row=(lane>>4)*4+reg
// ---------------------------------------------------------------------------
#define ASTRIDE 40
#define BSTRIDE 40

__global__ __launch_bounds__(256) void gemm_mfma_kernel(const float* __restrict__ A,
                                                        const short* __restrict__ Wt,
                                                        float* __restrict__ C) {
    __shared__ short As[64 * ASTRIDE];    // 5.0 KB
    __shared__ short Bs[256 * BSTRIDE];   // 20.0 KB

    const int tid  = threadIdx.x;
    const int wave = tid >> 6;
    const int lane = tid & 63;
    const int m0   = blockIdx.x * 64;
    const int n0w  = wave * 64;

    const int quad = lane >> 4;       // 0..3
    const int l16  = lane & 15;

    // A staging: thread t -> row ar = t>>2, float cols [aq*8, aq*8+8)
    const int ar = tid >> 2;
    const int aq = tid & 3;

    f32x4 zero4 = {0.f, 0.f, 0.f, 0.f};
    f32x4 acc[4][4];
#pragma unroll
    for (int i = 0; i < 4; ++i)
#pragma unroll
        for (int j = 0; j < 4; ++j) acc[i][j] = zero4;

    for (int k0 = 0; k0 < IN_F; k0 += 32) {
        // ---- stage A (64 x 32 fp32 -> bf16) ----
        {
            const int gm = m0 + ar;
            float4 v0 = make_float4(0.f, 0.f, 0.f, 0.f);
            float4 v1 = v0;
            if (gm < N_NODES) {
                const float* p = A + (size_t)gm * IN_F + k0 + aq * 8;
                v0 = *(const float4*)p;
                v1 = *(const float4*)(p + 4);
            }
            bf16x8 b;
            b[0] = bf16rne(v0.x); b[1] = bf16rne(v0.y);
            b[2] = bf16rne(v0.z); b[3] = bf16rne(v0.w);
            b[4] = bf16rne(v1.x); b[5] = bf16rne(v1.y);
            b[6] = bf16rne(v1.z); b[7] = bf16rne(v1.w);
            *(bf16x8*)&As[ar * ASTRIDE + aq * 8] = b;
        }
        // ---- stage B (256 x 32 bf16 from Wt, already transposed) ----
        {
            const short* src = Wt + (size_t)tid * IN_F + k0;   // row n=tid
            bf16x8 w0 = *(const bf16x8*)(src + 0);
            bf16x8 w1 = *(const bf16x8*)(src + 8);
            bf16x8 w2 = *(const bf16x8*)(src + 16);
            bf16x8 w3 = *(const bf16x8*)(src + 24);
            short* dst = &Bs[tid * BSTRIDE];
            *(bf16x8*)(dst + 0)  = w0;
            *(bf16x8*)(dst + 8)  = w1;
            *(bf16x8*)(dst + 16) = w2;
            *(bf16x8*)(dst + 24) = w3;
        }
        __syncthreads();

        bf16x8 af[4], bf[4];
#pragma unroll
        for (int mt = 0; mt < 4; ++mt)
            af[mt] = *(const bf16x8*)&As[(mt * 16 + l16) * ASTRIDE + quad * 8];
#pragma unroll
        for (int nt = 0; nt < 4; ++nt)
            bf[nt] = *(const bf16x8*)&Bs[(n0w + nt * 16 + l16) * BSTRIDE + quad * 8];

#pragma unroll
        for (int mt = 0; mt < 4; ++mt)
#pragma unroll
            for (int nt = 0; nt < 4; ++nt)
                acc[mt][nt] = __builtin_amdgcn_mfma_f32_16x16x32_bf16(
                    af[mt], bf[nt], acc[mt][nt], 0, 0, 0);
        __syncthreads();
    }

    // epilogue: C[row][col], row = m0 + mt*16 + quad*4 + i, col = n0w + nt*16 + l16
#pragma unroll
    for (int mt = 0; mt < 4; ++mt) {
        const int rbase = m0 + mt * 16 + quad * 4;
#pragma unroll
        for (int i = 0; i < 4; ++i) {
            const int row = rbase + i;
            if (row < N_NODES) {
#pragma unroll
                for (int nt = 0; nt < 4; ++nt)
                    C[(size_t)row * OUT_F + n0w + nt * 16 + l16] = acc[mt][nt][i];
            }
        }
    }
}

// ---------------------------------------------------------------------------
// CSR build: zero counts -> histogram -> hierarchical exclusive scan -> fill
// ---------------------------------------------------------------------------
__global__ __launch_bounds__(256) void zero_counts_kernel(int* __restrict__ counts) {
    int i = blockIdx.x * 256 + threadIdx.x;
    if (i < N_NODES) counts[i] = 0;
}

__global__ __launch_bounds__(256) void hist_kernel(const int* __restrict__ rows,
                                                   int* __restrict__ counts) {
    int e = blockIdx.x * 256 + threadIdx.x;
    if (e < N_EDGES) atomicAdd(&counts[rows[e]], 1);
}

__global__ __launch_bounds__(SCAN_B) void scan1_kernel(const int* __restrict__ counts,
                                                       int* __restrict__ excl,
                                                       int* __restrict__ blockSums) {
    __shared__ int s[SCAN_B];
    const int tid = threadIdx.x;
    const int i   = blockIdx.x * SCAN_B + tid;
    const int c   = (i < N_NODES) ? counts[i] : 0;
    s[tid] = c;
#pragma unroll
    for (int off = 1; off < SCAN_B; off <<= 1) {
        __syncthreads();
        int t = (tid >= off) ? s[tid - off] : 0;
        __syncthreads();
        s[tid] += t;
    }
    __syncthreads();
    if (i < N_NODES) excl[i] = s[tid] - c;
    if (tid == SCAN_B - 1) blockSums[blockIdx.x] = s[tid];
}

__global__ __launch_bounds__(SCAN_B) void scan2_kernel(int* __restrict__ blockSums,
                                                       int* __restrict__ blockOffs) {
    __shared__ int s[SCAN_B];
    const int tid = threadIdx.x;
    const int c = (tid < N_SCAN_BLOCKS) ? blockSums[tid] : 0;
    s[tid] = c;
#pragma unroll
    for (int off = 1; off < SCAN_B; off <<= 1) {
        __syncthreads();
        int t = (tid >= off) ? s[tid - off] : 0;
        __syncthreads();
        s[tid] += t;
    }
    __syncthreads();
    if (tid < N_SCAN_BLOCKS) blockOffs[tid] = s[tid] - c;
}

__global__ __launch_bounds__(SCAN_B) void scan3_kernel(int* __restrict__ excl,
                                                       const int* __restrict__ blockOffs,
                                                       int* __restrict__ cursor) {
    const int i = blockIdx.x * SCAN_B + threadIdx.x;
    if (i < N_NODES) {
        const int v = excl[i] + blockOffs[blockIdx.x];
        excl[i] = v;
        cursor[i] = v;
    }
}

__global__ __launch_bounds__(256) void fill_kernel(const int* __restrict__ rows,
                                                   const int* __restrict__ cols,
                                                   const float* __restrict__ vals,
                                                   int* __restrict__ cursor,
                                                   int* __restrict__ sorted_col,
                                                   float* __restrict__ sorted_val) {
    int e = blockIdx.x * 256 + threadIdx.x;
    if (e < N_EDGES) {
        const int pos = atomicAdd(&cursor[rows[e]], 1);
        sorted_col[pos] = cols[e];
        sorted_val[pos] = vals[e];
    }
}

// ---------------------------------------------------------------------------
// Gather: one wave per output row. lane holds float4 (OUT_F/4 = 64 = lanes).
// ---------------------------------------------------------------------------
__global__ __launch_bounds__(256) void gather_kernel(const float4* __restrict__ support,
                                                     const int* __restrict__ excl,
                                                     const int* __restrict__ counts,
                                                     const int* __restrict__ sorted_col,
                                                     const float* __restrict__ sorted_val,
                                                     float4* __restrict__ out) {
    const int tid  = threadIdx.x;
    const int row  = blockIdx.x * 4 + (tid >> 6);
    const int lane = tid & 63;
    if (row >= N_NODES) return;

    const int start = excl[row];
    const int end   = start + counts[row];

    float4 acc = make_float4(0.f, 0.f, 0.f, 0.f);
    int e = start;
    for (; e + 1 < end; e += 2) {
        const int   c0 = sorted_col[e];
        const int   c1 = sorted_col[e + 1];
        const float v0 = sorted_val[e];
        const float v1 = sorted_val[e + 1];
        const float4 s0 = support[(size_t)c0 * 64 + lane];
        const float4 s1 = support[(size_t)c1 * 64 + lane];
        acc.x += v0 * s0.x; acc.y += v0 * s0.y; acc.z += v0 * s0.z; acc.w += v0 * s0.w;
        acc.x += v1 * s1.x; acc.y += v1 * s1.y; acc.z += v1 * s1.z; acc.w += v1 * s1.w;
    }
    if (e < end) {
        const int   c0 = sorted_col[e];
        const float v0 = sorted_val[e];
        const float4 s0 = support[(size_t)c0 * 64 + lane];
        acc.x += v0 * s0.x; acc.y += v0 * s0.y; acc.z += v0 * s0.z; acc.w += v0 * s0.w;
    }

    acc.x = fmaxf(acc.x, 0.f);
    acc.y = fmaxf(acc.y, 0.f);
    acc.z = fmaxf(acc.z, 0.f);
    acc.w = fmaxf(acc.w, 0.f);
    out[(size_t)row * 64 + lane] = acc;
}

extern "C" void kernel_launch(void* const* d_in, const int* in_sizes, int n_in,
                              void* d_out, int out_size, void* d_ws, size_t ws_size,
                              hipStream_t stream) {
    const float* features  = (const float*)d_in[0];   // [50000, 512]
    const float* weight    = (const float*)d_in[1];   // [512, 256]
    const float* edge_vals = (const float*)d_in[2];   // [1.6M]
    const int*   edge_rows = (const int*)d_in[3];
    const int*   edge_cols = (const int*)d_in[4];
    float* out = (float*)d_out;                       // [50000, 256]

    // workspace layout
    float* support    = (float*)d_ws;                               // 12.8M floats
    int*   counts     = (int*)(support + (size_t)N_NODES * OUT_F);  // 50000
    int*   excl       = counts + N_NODES;                           // 50000
    int*   cursor     = excl + N_NODES;                             // 50000
    int*   blockSums  = cursor + N_NODES;                           // 256
    int*   blockOffs  = blockSums + 256;                            // 256
    int*   sorted_col = blockOffs + 256;                            // 1.6M
    float* sorted_val = (float*)(sorted_col + N_EDGES);             // 1.6M
    short* Wt         = (short*)(sorted_val + N_EDGES);             // 131072 bf16

    // 1) weight transpose + bf16 convert
    wt_kernel<<<(IN_F * OUT_F + 255) / 256, 256, 0, stream>>>(weight, Wt);

    // 2) MFMA GEMM: support = features @ weight (bf16 inputs, fp32 acc)
    gemm_mfma_kernel<<<(N_NODES + 63) / 64, 256, 0, stream>>>(features, Wt, support);

    // 3) CSR build (counting sort by destination row)
    zero_counts_kernel<<<(N_NODES + 255) / 256, 256, 0, stream>>>(counts);
    hist_kernel<<<(N_EDGES + 255) / 256, 256, 0, stream>>>(edge_rows, counts);
    scan1_kernel<<<N_SCAN_BLOCKS, SCAN_B, 0, stream>>>(counts, excl, blockSums);
    scan2_kernel<<<1, SCAN_B, 0, stream>>>(blockSums, blockOffs);
    scan3_kernel<<<N_SCAN_BLOCKS, SCAN_B, 0, stream>>>(excl, blockOffs, cursor);
    fill_kernel<<<(N_EDGES + 255) / 256, 256, 0, stream>>>(
        edge_rows, edge_cols, edge_vals, cursor, sorted_col, sorted_val);

    // 4) gather + fused ReLU (one wave per row, no atomics)
    gather_kernel<<<(N_NODES + 3) / 4, 256, 0, stream>>>(
        (const float4*)support, excl, counts, sorted_col, sorted_val, (float4*)out);
}

// Round 5
// 505.631 us; speedup vs baseline: 11.1159x; 1.2115x over previous
//
#include <hip/hip_runtime.h>

#define N_NODES 50000
#define N_EDGES 1600000
#define IN_F    512
#define OUT_F   256

#define SCAN_B  256
#define N_SCAN_BLOCKS ((N_NODES + SCAN_B - 1) / SCAN_B)   // 196

typedef __attribute__((ext_vector_type(8))) short bf16x8;
typedef __attribute__((ext_vector_type(4))) float f32x4;

__device__ __forceinline__ short bf16rne(float f) {
    unsigned u = __builtin_bit_cast(unsigned, f);
    u += 0x7fffu + ((u >> 16) & 1u);          // round-to-nearest-even
    return (short)(u >> 16);
}

__device__ __forceinline__ float b2f(unsigned short h) {
    unsigned u = (unsigned)h << 16;
    return __builtin_bit_cast(float, u);
}

// ---------------------------------------------------------------------------
// Kernel 0: Wt[n][k] = bf16(W[k][n])  — transpose + convert weight (512x256)
// ---------------------------------------------------------------------------
__global__ __launch_bounds__(256) void wt_kernel(const float* __restrict__ W,
                                                 short* __restrict__ Wt) {
    int idx = blockIdx.x * 256 + threadIdx.x;
    if (idx < IN_F * OUT_F) {
        int n = idx >> 9;          // /512
        int k = idx & 511;
        Wt[idx] = bf16rne(W[(size_t)k * OUT_F + n]);
    }
}

// ---------------------------------------------------------------------------
// Kernel 1: support(bf16) = features @ weight via bf16 MFMA.
// BM=64, BN=256 (full N -> A read once), BK=32. 4 waves, wave owns 64 cols.
// Epilogue converts fp32 acc -> bf16 and stores support as bf16 (halves
// gather-side traffic).
// ---------------------------------------------------------------------------
#define ASTRIDE 40
#define BSTRIDE 40

__global__ __launch_bounds__(256) void gemm_mfma_kernel(const float* __restrict__ A,
                                                        const short* __restrict__ Wt,
                                                        unsigned short* __restrict__ Cb) {
    __shared__ short As[64 * ASTRIDE];
    __shared__ short Bs[256 * BSTRIDE];

    const int tid  = threadIdx.x;
    const int wave = tid >> 6;
    const int lane = tid & 63;
    const int m0   = blockIdx.x * 64;
    const int n0w  = wave * 64;

    const int quad = lane >> 4;
    const int l16  = lane & 15;

    const int ar = tid >> 2;
    const int aq = tid & 3;

    f32x4 zero4 = {0.f, 0.f, 0.f, 0.f};
    f32x4 acc[4][4];
#pragma unroll
    for (int i = 0; i < 4; ++i)
#pragma unroll
        for (int j = 0; j < 4; ++j) acc[i][j] = zero4;

    for (int k0 = 0; k0 < IN_F; k0 += 32) {
        {
            const int gm = m0 + ar;
            float4 v0 = make_float4(0.f, 0.f, 0.f, 0.f);
            float4 v1 = v0;
            if (gm < N_NODES) {
                const float* p = A + (size_t)gm * IN_F + k0 + aq * 8;
                v0 = *(const float4*)p;
                v1 = *(const float4*)(p + 4);
            }
            bf16x8 b;
            b[0] = bf16rne(v0.x); b[1] = bf16rne(v0.y);
            b[2] = bf16rne(v0.z); b[3] = bf16rne(v0.w);
            b[4] = bf16rne(v1.x); b[5] = bf16rne(v1.y);
            b[6] = bf16rne(v1.z); b[7] = bf16rne(v1.w);
            *(bf16x8*)&As[ar * ASTRIDE + aq * 8] = b;
        }
        {
            const short* src = Wt + (size_t)tid * IN_F + k0;
            bf16x8 w0 = *(const bf16x8*)(src + 0);
            bf16x8 w1 = *(const bf16x8*)(src + 8);
            bf16x8 w2 = *(const bf16x8*)(src + 16);
            bf16x8 w3 = *(const bf16x8*)(src + 24);
            short* dst = &Bs[tid * BSTRIDE];
            *(bf16x8*)(dst + 0)  = w0;
            *(bf16x8*)(dst + 8)  = w1;
            *(bf16x8*)(dst + 16) = w2;
            *(bf16x8*)(dst + 24) = w3;
        }
        __syncthreads();

        bf16x8 af[4], bf[4];
#pragma unroll
        for (int mt = 0; mt < 4; ++mt)
            af[mt] = *(const bf16x8*)&As[(mt * 16 + l16) * ASTRIDE + quad * 8];
#pragma unroll
        for (int nt = 0; nt < 4; ++nt)
            bf[nt] = *(const bf16x8*)&Bs[(n0w + nt * 16 + l16) * BSTRIDE + quad * 8];

#pragma unroll
        for (int mt = 0; mt < 4; ++mt)
#pragma unroll
            for (int nt = 0; nt < 4; ++nt)
                acc[mt][nt] = __builtin_amdgcn_mfma_f32_16x16x32_bf16(
                    af[mt], bf[nt], acc[mt][nt], 0, 0, 0);
        __syncthreads();
    }

    // epilogue: bf16 store. row = m0 + mt*16 + quad*4 + i, col = n0w + nt*16 + l16
#pragma unroll
    for (int mt = 0; mt < 4; ++mt) {
        const int rbase = m0 + mt * 16 + quad * 4;
#pragma unroll
        for (int i = 0; i < 4; ++i) {
            const int row = rbase + i;
            if (row < N_NODES) {
#pragma unroll
                for (int nt = 0; nt < 4; ++nt)
                    Cb[(size_t)row * OUT_F + n0w + nt * 16 + l16] =
                        (unsigned short)bf16rne(acc[mt][nt][i]);
            }
        }
    }
}

// ---------------------------------------------------------------------------
// CSR build: zero counts -> histogram -> hierarchical exclusive scan -> fill
// ---------------------------------------------------------------------------
__global__ __launch_bounds__(256) void zero_counts_kernel(int* __restrict__ counts) {
    int i = blockIdx.x * 256 + threadIdx.x;
    if (i < N_NODES) counts[i] = 0;
}

__global__ __launch_bounds__(256) void hist_kernel(const int* __restrict__ rows,
                                                   int* __restrict__ counts) {
    int e = blockIdx.x * 256 + threadIdx.x;
    if (e < N_EDGES) atomicAdd(&counts[rows[e]], 1);
}

__global__ __launch_bounds__(SCAN_B) void scan1_kernel(const int* __restrict__ counts,
                                                       int* __restrict__ excl,
                                                       int* __restrict__ blockSums) {
    __shared__ int s[SCAN_B];
    const int tid = threadIdx.x;
    const int i   = blockIdx.x * SCAN_B + tid;
    const int c   = (i < N_NODES) ? counts[i] : 0;
    s[tid] = c;
#pragma unroll
    for (int off = 1; off < SCAN_B; off <<= 1) {
        __syncthreads();
        int t = (tid >= off) ? s[tid - off] : 0;
        __syncthreads();
        s[tid] += t;
    }
    __syncthreads();
    if (i < N_NODES) excl[i] = s[tid] - c;
    if (tid == SCAN_B - 1) blockSums[blockIdx.x] = s[tid];
}

__global__ __launch_bounds__(SCAN_B) void scan2_kernel(int* __restrict__ blockSums,
                                                       int* __restrict__ blockOffs) {
    __shared__ int s[SCAN_B];
    const int tid = threadIdx.x;
    const int c = (tid < N_SCAN_BLOCKS) ? blockSums[tid] : 0;
    s[tid] = c;
#pragma unroll
    for (int off = 1; off < SCAN_B; off <<= 1) {
        __syncthreads();
        int t = (tid >= off) ? s[tid - off] : 0;
        __syncthreads();
        s[tid] += t;
    }
    __syncthreads();
    if (tid < N_SCAN_BLOCKS) blockOffs[tid] = s[tid] - c;
}

__global__ __launch_bounds__(SCAN_B) void scan3_kernel(int* __restrict__ excl,
                                                       const int* __restrict__ blockOffs,
                                                       int* __restrict__ cursor) {
    const int i = blockIdx.x * SCAN_B + threadIdx.x;
    if (i < N_NODES) {
        const int v = excl[i] + blockOffs[blockIdx.x];
        excl[i] = v;
        cursor[i] = v;
    }
}

// fill packs (col, val) into one int2 -> single 8 B store per edge
__global__ __launch_bounds__(256) void fill_kernel(const int* __restrict__ rows,
                                                   const int* __restrict__ cols,
                                                   const float* __restrict__ vals,
                                                   int* __restrict__ cursor,
                                                   int2* __restrict__ ecv) {
    int e = blockIdx.x * 256 + threadIdx.x;
    if (e < N_EDGES) {
        const int pos = atomicAdd(&cursor[rows[e]], 1);
        ecv[pos] = make_int2(cols[e], __float_as_int(vals[e]));
    }
}

// ---------------------------------------------------------------------------
// Gather: one wave per output row. support is bf16: lane holds ushort4 (8 B),
// 64 lanes * 4 bf16 = 256 cols. 4-edge unroll for MLP. fp32 accumulate.
// ---------------------------------------------------------------------------
__global__ __launch_bounds__(256) void gather_kernel(const ushort4* __restrict__ support,
                                                     const int* __restrict__ excl,
                                                     const int2* __restrict__ ecv,
                                                     float4* __restrict__ out) {
    const int tid  = threadIdx.x;
    const int row  = blockIdx.x * 4 + (tid >> 6);
    const int lane = tid & 63;
    if (row >= N_NODES) return;

    const int start = excl[row];
    const int end   = (row + 1 < N_NODES) ? excl[row + 1] : N_EDGES;

    float4 acc = make_float4(0.f, 0.f, 0.f, 0.f);
    int e = start;
    const int end4 = start + ((end - start) & ~3);
    for (; e < end4; e += 4) {
        const int2 p0 = ecv[e];
        const int2 p1 = ecv[e + 1];
        const int2 p2 = ecv[e + 2];
        const int2 p3 = ecv[e + 3];
        const ushort4 s0 = support[(size_t)p0.x * 64 + lane];
        const ushort4 s1 = support[(size_t)p1.x * 64 + lane];
        const ushort4 s2 = support[(size_t)p2.x * 64 + lane];
        const ushort4 s3 = support[(size_t)p3.x * 64 + lane];
        const float v0 = __int_as_float(p0.y);
        const float v1 = __int_as_float(p1.y);
        const float v2 = __int_as_float(p2.y);
        const float v3 = __int_as_float(p3.y);
        acc.x += v0 * b2f(s0.x); acc.y += v0 * b2f(s0.y);
        acc.z += v0 * b2f(s0.z); acc.w += v0 * b2f(s0.w);
        acc.x += v1 * b2f(s1.x); acc.y += v1 * b2f(s1.y);
        acc.z += v1 * b2f(s1.z); acc.w += v1 * b2f(s1.w);
        acc.x += v2 * b2f(s2.x); acc.y += v2 * b2f(s2.y);
        acc.z += v2 * b2f(s2.z); acc.w += v2 * b2f(s2.w);
        acc.x += v3 * b2f(s3.x); acc.y += v3 * b2f(s3.y);
        acc.z += v3 * b2f(s3.z); acc.w += v3 * b2f(s3.w);
    }
    for (; e < end; ++e) {
        const int2 p0 = ecv[e];
        const ushort4 s0 = support[(size_t)p0.x * 64 + lane];
        const float v0 = __int_as_float(p0.y);
        acc.x += v0 * b2f(s0.x); acc.y += v0 * b2f(s0.y);
        acc.z += v0 * b2f(s0.z); acc.w += v0 * b2f(s0.w);
    }

    acc.x = fmaxf(acc.x, 0.f);
    acc.y = fmaxf(acc.y, 0.f);
    acc.z = fmaxf(acc.z, 0.f);
    acc.w = fmaxf(acc.w, 0.f);
    out[(size_t)row * 64 + lane] = acc;
}

extern "C" void kernel_launch(void* const* d_in, const int* in_sizes, int n_in,
                              void* d_out, int out_size, void* d_ws, size_t ws_size,
                              hipStream_t stream) {
    const float* features  = (const float*)d_in[0];   // [50000, 512]
    const float* weight    = (const float*)d_in[1];   // [512, 256]
    const float* edge_vals = (const float*)d_in[2];   // [1.6M]
    const int*   edge_rows = (const int*)d_in[3];
    const int*   edge_cols = (const int*)d_in[4];
    float* out = (float*)d_out;                       // [50000, 256]

    // workspace layout (all 8B-aligned)
    unsigned short* support_bf = (unsigned short*)d_ws;             // 12.8M bf16 (25.6 MB)
    int2*  ecv        = (int2*)(support_bf + (size_t)N_NODES * OUT_F); // 1.6M int2 (12.8 MB)
    int*   counts     = (int*)(ecv + N_EDGES);                      // 50000
    int*   excl       = counts + N_NODES;                           // 50000
    int*   cursor     = excl + N_NODES;                             // 50000
    int*   blockSums  = cursor + N_NODES;                           // 256
    int*   blockOffs  = blockSums + 256;                            // 256
    short* Wt         = (short*)(blockOffs + 256);                  // 131072 bf16

    // 1) weight transpose + bf16 convert
    wt_kernel<<<(IN_F * OUT_F + 255) / 256, 256, 0, stream>>>(weight, Wt);

    // 2) MFMA GEMM: support(bf16) = features @ weight
    gemm_mfma_kernel<<<(N_NODES + 63) / 64, 256, 0, stream>>>(features, Wt, support_bf);

    // 3) CSR build (counting sort by destination row)
    zero_counts_kernel<<<(N_NODES + 255) / 256, 256, 0, stream>>>(counts);
    hist_kernel<<<(N_EDGES + 255) / 256, 256, 0, stream>>>(edge_rows, counts);
    scan1_kernel<<<N_SCAN_BLOCKS, SCAN_B, 0, stream>>>(counts, excl, blockSums);
    scan2_kernel<<<1, SCAN_B, 0, stream>>>(blockSums, blockOffs);
    scan3_kernel<<<N_SCAN_BLOCKS, SCAN_B, 0, stream>>>(excl, blockOffs, cursor);
    fill_kernel<<<(N_EDGES + 255) / 256, 256, 0, stream>>>(
        edge_rows, edge_cols, edge_vals, cursor, ecv);

    // 4) gather + fused ReLU (one wave per row, no atomics)
    gather_kernel<<<(N_NODES + 3) / 4, 256, 0, stream>>>(
        (const ushort4*)support_bf, excl, ecv, (float4*)out);
}

// Round 6
// 403.076 us; speedup vs baseline: 13.9441x; 1.2544x over previous
//
#include <hip/hip_runtime.h>

#define N_NODES 50000
#define N_EDGES 1600000
#define IN_F    512
#define OUT_F   256

// two-pass sort params
#define NBINS   98              // ceil(50000 / 512)
#define BROWS   512             // rows per coarse bucket
#define BATCH   2048            // edges per fillA block
#define NBATCHES ((N_EDGES + BATCH - 1) / BATCH)   // 782

typedef __attribute__((ext_vector_type(8))) short bf16x8;
typedef __attribute__((ext_vector_type(4))) float f32x4;

__device__ __forceinline__ short bf16rne(float f) {
    unsigned u = __builtin_bit_cast(unsigned, f);
    u += 0x7fffu + ((u >> 16) & 1u);          // round-to-nearest-even
    return (short)(u >> 16);
}

__device__ __forceinline__ float b2f(unsigned short h) {
    unsigned u = (unsigned)h << 16;
    return __builtin_bit_cast(float, u);
}

// ---------------------------------------------------------------------------
// Kernel 0: Wt[n][k] = bf16(W[k][n])  — transpose + convert weight (512x256)
// ---------------------------------------------------------------------------
__global__ __launch_bounds__(256) void wt_kernel(const float* __restrict__ W,
                                                 short* __restrict__ Wt) {
    int idx = blockIdx.x * 256 + threadIdx.x;
    if (idx < IN_F * OUT_F) {
        int n = idx >> 9;          // /512
        int k = idx & 511;
        Wt[idx] = bf16rne(W[(size_t)k * OUT_F + n]);
    }
}

// ---------------------------------------------------------------------------
// Kernel 1: support(bf16) = features @ weight via bf16 MFMA.
// BM=64, BN=256 (full N -> A read once), BK=32. 4 waves, wave owns 64 cols.
// ---------------------------------------------------------------------------
#define ASTRIDE 40
#define BSTRIDE 40

__global__ __launch_bounds__(256) void gemm_mfma_kernel(const float* __restrict__ A,
                                                        const short* __restrict__ Wt,
                                                        unsigned short* __restrict__ Cb) {
    __shared__ short As[64 * ASTRIDE];
    __shared__ short Bs[256 * BSTRIDE];

    const int tid  = threadIdx.x;
    const int wave = tid >> 6;
    const int lane = tid & 63;
    const int m0   = blockIdx.x * 64;
    const int n0w  = wave * 64;

    const int quad = lane >> 4;
    const int l16  = lane & 15;

    const int ar = tid >> 2;
    const int aq = tid & 3;

    f32x4 zero4 = {0.f, 0.f, 0.f, 0.f};
    f32x4 acc[4][4];
#pragma unroll
    for (int i = 0; i < 4; ++i)
#pragma unroll
        for (int j = 0; j < 4; ++j) acc[i][j] = zero4;

    for (int k0 = 0; k0 < IN_F; k0 += 32) {
        {
            const int gm = m0 + ar;
            float4 v0 = make_float4(0.f, 0.f, 0.f, 0.f);
            float4 v1 = v0;
            if (gm < N_NODES) {
                const float* p = A + (size_t)gm * IN_F + k0 + aq * 8;
                v0 = *(const float4*)p;
                v1 = *(const float4*)(p + 4);
            }
            bf16x8 b;
            b[0] = bf16rne(v0.x); b[1] = bf16rne(v0.y);
            b[2] = bf16rne(v0.z); b[3] = bf16rne(v0.w);
            b[4] = bf16rne(v1.x); b[5] = bf16rne(v1.y);
            b[6] = bf16rne(v1.z); b[7] = bf16rne(v1.w);
            *(bf16x8*)&As[ar * ASTRIDE + aq * 8] = b;
        }
        {
            const short* src = Wt + (size_t)tid * IN_F + k0;
            bf16x8 w0 = *(const bf16x8*)(src + 0);
            bf16x8 w1 = *(const bf16x8*)(src + 8);
            bf16x8 w2 = *(const bf16x8*)(src + 16);
            bf16x8 w3 = *(const bf16x8*)(src + 24);
            short* dst = &Bs[tid * BSTRIDE];
            *(bf16x8*)(dst + 0)  = w0;
            *(bf16x8*)(dst + 8)  = w1;
            *(bf16x8*)(dst + 16) = w2;
            *(bf16x8*)(dst + 24) = w3;
        }
        __syncthreads();

        bf16x8 af[4], bf[4];
#pragma unroll
        for (int mt = 0; mt < 4; ++mt)
            af[mt] = *(const bf16x8*)&As[(mt * 16 + l16) * ASTRIDE + quad * 8];
#pragma unroll
        for (int nt = 0; nt < 4; ++nt)
            bf[nt] = *(const bf16x8*)&Bs[(n0w + nt * 16 + l16) * BSTRIDE + quad * 8];

#pragma unroll
        for (int mt = 0; mt < 4; ++mt)
#pragma unroll
            for (int nt = 0; nt < 4; ++nt)
                acc[mt][nt] = __builtin_amdgcn_mfma_f32_16x16x32_bf16(
                    af[mt], bf[nt], acc[mt][nt], 0, 0, 0);
        __syncthreads();
    }

#pragma unroll
    for (int mt = 0; mt < 4; ++mt) {
        const int rbase = m0 + mt * 16 + quad * 4;
#pragma unroll
        for (int i = 0; i < 4; ++i) {
            const int row = rbase + i;
            if (row < N_NODES) {
#pragma unroll
                for (int nt = 0; nt < 4; ++nt)
                    Cb[(size_t)row * OUT_F + n0w + nt * 16 + l16] =
                        (unsigned short)bf16rne(acc[mt][nt][i]);
            }
        }
    }
}

// ---------------------------------------------------------------------------
// Two-pass edge sort.
// Pass A: coarse bin by row>>9 into 98 buckets, LDS-staged for coalesced
//         writes. Entry packed: x = (row&511)<<16 | col (col < 65536), y = val.
// Pass B: per-bucket counting sort over 512 local rows; scatter window is
//         ~131 KB -> L2-resident, no write amplification. Emits global excl.
// ---------------------------------------------------------------------------
__global__ __launch_bounds__(256) void zero_bins_kernel(int* __restrict__ binCounts) {
    if (threadIdx.x < NBINS) binCounts[threadIdx.x] = 0;
}

__global__ __launch_bounds__(256) void histA_kernel(const int* __restrict__ rows,
                                                    int* __restrict__ binCounts) {
    __shared__ int lh[NBINS];
    const int tid = threadIdx.x;
    if (tid < NBINS) lh[tid] = 0;
    __syncthreads();
    for (int i = blockIdx.x * 256 + tid; i < N_EDGES; i += gridDim.x * 256)
        atomicAdd(&lh[rows[i] >> 9], 1);
    __syncthreads();
    if (tid < NBINS) atomicAdd(&binCounts[tid], lh[tid]);
}

__global__ __launch_bounds__(256) void scanA_kernel(const int* __restrict__ binCounts,
                                                    int* __restrict__ binStart,
                                                    int* __restrict__ gcursor) {
    __shared__ int s[128];
    const int tid = threadIdx.x;
    const int c = (tid < NBINS) ? binCounts[tid] : 0;
    if (tid < 128) s[tid] = c;
    for (int off = 1; off < 128; off <<= 1) {
        __syncthreads();
        int t = (tid >= off && tid < 128) ? s[tid - off] : 0;
        __syncthreads();
        if (tid < 128) s[tid] += t;
    }
    __syncthreads();
    if (tid < NBINS) {
        const int st = s[tid] - c;
        binStart[tid] = st;
        gcursor[tid]  = st;
    }
}

__global__ __launch_bounds__(256) void fillA_kernel(const int* __restrict__ rows,
                                                    const int* __restrict__ cols,
                                                    const float* __restrict__ vals,
                                                    int* __restrict__ gcursor,
                                                    int2* __restrict__ binned) {
    __shared__ int lhist[NBINS];
    __shared__ int lexcl[NBINS];
    __shared__ int gbase[NBINS];
    __shared__ int stmp[128];
    __shared__ int2 lstage[BATCH];
    __shared__ unsigned char sbucket[BATCH];

    const int tid   = threadIdx.x;
    const int start = blockIdx.x * BATCH;
    const int count = min(BATCH, N_EDGES - start);

    if (tid < NBINS) lhist[tid] = 0;
    __syncthreads();

    int myrow[8], myrank[8];
#pragma unroll
    for (int j = 0; j < 8; ++j) {
        const int s = j * 256 + tid;
        if (s < count) {
            const int r = rows[start + s];
            myrow[j]  = r;
            myrank[j] = atomicAdd(&lhist[r >> 9], 1);
        }
    }
    __syncthreads();

    // scan lhist (98) + reserve global space per bucket
    const int c = (tid < NBINS) ? lhist[tid] : 0;
    if (tid < 128) stmp[tid] = c;
    for (int off = 1; off < 128; off <<= 1) {
        __syncthreads();
        int t = (tid >= off && tid < 128) ? stmp[tid - off] : 0;
        __syncthreads();
        if (tid < 128) stmp[tid] += t;
    }
    __syncthreads();
    if (tid < NBINS) {
        lexcl[tid] = stmp[tid] - c;
        gbase[tid] = c ? atomicAdd(&gcursor[tid], c) : 0;
    }
    __syncthreads();

    // stage into LDS ordered by bucket
#pragma unroll
    for (int j = 0; j < 8; ++j) {
        const int s = j * 256 + tid;
        if (s < count) {
            const int r   = myrow[j];
            const int b   = r >> 9;
            const int pos = lexcl[b] + myrank[j];
            lstage[pos]  = make_int2(((r & 511) << 16) | cols[start + s],
                                     __float_as_int(vals[start + s]));
            sbucket[pos] = (unsigned char)b;
        }
    }
    __syncthreads();

    // write out: bucket runs are contiguous -> coalesced-ish stores
#pragma unroll
    for (int j = 0; j < 8; ++j) {
        const int s = j * 256 + tid;
        if (s < count) {
            const int b = sbucket[s];
            binned[gbase[b] + (s - lexcl[b])] = lstage[s];
        }
    }
}

__global__ __launch_bounds__(256) void sortB_kernel(const int2* __restrict__ binned,
                                                    const int* __restrict__ binStart,
                                                    const int* __restrict__ binCounts,
                                                    int* __restrict__ excl,
                                                    int2* __restrict__ ecv) {
    __shared__ int lhist[BROWS];
    __shared__ int lcur[BROWS];
    __shared__ int stmp[256];

    const int tid  = threadIdx.x;
    const int b    = blockIdx.x;
    const int base = binStart[b];
    const int cnt  = binCounts[b];

    lhist[tid] = 0;
    lhist[tid + 256] = 0;
    __syncthreads();

    for (int i = tid; i < cnt; i += 256)
        atomicAdd(&lhist[binned[base + i].x >> 16], 1);
    __syncthreads();

    // scan 512 with 256 threads (2 rows per thread)
    const int a0 = lhist[2 * tid];
    const int a1 = lhist[2 * tid + 1];
    const int pair = a0 + a1;
    stmp[tid] = pair;
    for (int off = 1; off < 256; off <<= 1) {
        __syncthreads();
        int t = (tid >= off) ? stmp[tid - off] : 0;
        __syncthreads();
        stmp[tid] += t;
    }
    __syncthreads();
    const int pexcl = stmp[tid] - pair;
    {
        const int rl0  = 2 * tid;
        const int row0 = b * BROWS + rl0;
        lcur[rl0]     = pexcl;
        lcur[rl0 + 1] = pexcl + a0;
        if (row0 < N_NODES)     excl[row0]     = base + pexcl;
        if (row0 + 1 < N_NODES) excl[row0 + 1] = base + pexcl + a0;
    }
    __syncthreads();

    for (int i = tid; i < cnt; i += 256) {
        const int2 e  = binned[base + i];
        const int rl  = e.x >> 16;
        const int col = e.x & 0xFFFF;
        const int rank = atomicAdd(&lcur[rl], 1);
        ecv[base + rank] = make_int2(col, e.y);
    }
}

// ---------------------------------------------------------------------------
// Gather: one wave per output row, support bf16 (ushort4/lane), 4-edge unroll.
// ---------------------------------------------------------------------------
__global__ __launch_bounds__(256) void gather_kernel(const ushort4* __restrict__ support,
                                                     const int* __restrict__ excl,
                                                     const int2* __restrict__ ecv,
                                                     float4* __restrict__ out) {
    const int tid  = threadIdx.x;
    const int row  = blockIdx.x * 4 + (tid >> 6);
    const int lane = tid & 63;
    if (row >= N_NODES) return;

    const int start = excl[row];
    const int end   = (row + 1 < N_NODES) ? excl[row + 1] : N_EDGES;

    float4 acc = make_float4(0.f, 0.f, 0.f, 0.f);
    int e = start;
    const int end4 = start + ((end - start) & ~3);
    for (; e < end4; e += 4) {
        const int2 p0 = ecv[e];
        const int2 p1 = ecv[e + 1];
        const int2 p2 = ecv[e + 2];
        const int2 p3 = ecv[e + 3];
        const ushort4 s0 = support[(size_t)p0.x * 64 + lane];
        const ushort4 s1 = support[(size_t)p1.x * 64 + lane];
        const ushort4 s2 = support[(size_t)p2.x * 64 + lane];
        const ushort4 s3 = support[(size_t)p3.x * 64 + lane];
        const float v0 = __int_as_float(p0.y);
        const float v1 = __int_as_float(p1.y);
        const float v2 = __int_as_float(p2.y);
        const float v3 = __int_as_float(p3.y);
        acc.x += v0 * b2f(s0.x); acc.y += v0 * b2f(s0.y);
        acc.z += v0 * b2f(s0.z); acc.w += v0 * b2f(s0.w);
        acc.x += v1 * b2f(s1.x); acc.y += v1 * b2f(s1.y);
        acc.z += v1 * b2f(s1.z); acc.w += v1 * b2f(s1.w);
        acc.x += v2 * b2f(s2.x); acc.y += v2 * b2f(s2.y);
        acc.z += v2 * b2f(s2.z); acc.w += v2 * b2f(s2.w);
        acc.x += v3 * b2f(s3.x); acc.y += v3 * b2f(s3.y);
        acc.z += v3 * b2f(s3.z); acc.w += v3 * b2f(s3.w);
    }
    for (; e < end; ++e) {
        const int2 p0 = ecv[e];
        const ushort4 s0 = support[(size_t)p0.x * 64 + lane];
        const float v0 = __int_as_float(p0.y);
        acc.x += v0 * b2f(s0.x); acc.y += v0 * b2f(s0.y);
        acc.z += v0 * b2f(s0.z); acc.w += v0 * b2f(s0.w);
    }

    acc.x = fmaxf(acc.x, 0.f);
    acc.y = fmaxf(acc.y, 0.f);
    acc.z = fmaxf(acc.z, 0.f);
    acc.w = fmaxf(acc.w, 0.f);
    out[(size_t)row * 64 + lane] = acc;
}

extern "C" void kernel_launch(void* const* d_in, const int* in_sizes, int n_in,
                              void* d_out, int out_size, void* d_ws, size_t ws_size,
                              hipStream_t stream) {
    const float* features  = (const float*)d_in[0];   // [50000, 512]
    const float* weight    = (const float*)d_in[1];   // [512, 256]
    const float* edge_vals = (const float*)d_in[2];   // [1.6M]
    const int*   edge_rows = (const int*)d_in[3];
    const int*   edge_cols = (const int*)d_in[4];
    float* out = (float*)d_out;                       // [50000, 256]

    // workspace layout (8B-aligned chunks first)
    unsigned short* support_bf = (unsigned short*)d_ws;                 // 25.6 MB
    int2*  binned    = (int2*)(support_bf + (size_t)N_NODES * OUT_F);   // 12.8 MB
    int2*  ecv       = binned + N_EDGES;                                // 12.8 MB
    int*   excl      = (int*)(ecv + N_EDGES);                           // 50000
    int*   binCounts = excl + N_NODES;                                  // 128
    int*   binStart  = binCounts + 128;                                 // 128
    int*   gcursor   = binStart + 128;                                  // 128
    short* Wt        = (short*)(gcursor + 128);                         // 131072 bf16

    // 1) weight transpose + bf16 convert
    wt_kernel<<<(IN_F * OUT_F + 255) / 256, 256, 0, stream>>>(weight, Wt);

    // 2) MFMA GEMM: support(bf16) = features @ weight
    gemm_mfma_kernel<<<(N_NODES + 63) / 64, 256, 0, stream>>>(features, Wt, support_bf);

    // 3) two-pass edge sort
    zero_bins_kernel<<<1, 256, 0, stream>>>(binCounts);
    histA_kernel<<<256, 256, 0, stream>>>(edge_rows, binCounts);
    scanA_kernel<<<1, 256, 0, stream>>>(binCounts, binStart, gcursor);
    fillA_kernel<<<NBATCHES, 256, 0, stream>>>(edge_rows, edge_cols, edge_vals,
                                               gcursor, binned);
    sortB_kernel<<<NBINS, 256, 0, stream>>>(binned, binStart, binCounts, excl, ecv);

    // 4) gather + fused ReLU (one wave per row, no atomics)
    gather_kernel<<<(N_NODES + 3) / 4, 256, 0, stream>>>(
        (const ushort4*)support_bf, excl, ecv, (float4*)out);
}

// Round 7
// 387.540 us; speedup vs baseline: 14.5031x; 1.0401x over previous
//
#include <hip/hip_runtime.h>

#define N_NODES 50000
#define N_EDGES 1600000
#define IN_F    512
#define OUT_F   256

// two-pass sort params: fine buckets of 128 rows
#define BROWS   128
#define NBINS   ((N_NODES + BROWS - 1) / BROWS)    // 391
#define BATCH   2048
#define NBATCHES ((N_EDGES + BATCH - 1) / BATCH)   // 782

typedef __attribute__((ext_vector_type(8))) short bf16x8;
typedef __attribute__((ext_vector_type(4))) float f32x4;

__device__ __forceinline__ short bf16rne(float f) {
    unsigned u = __builtin_bit_cast(unsigned, f);
    u += 0x7fffu + ((u >> 16) & 1u);          // round-to-nearest-even
    return (short)(u >> 16);
}

__device__ __forceinline__ float b2f(unsigned short h) {
    unsigned u = (unsigned)h << 16;
    return __builtin_bit_cast(float, u);
}

// ---------------------------------------------------------------------------
// Kernel 0: Wt[n][k] = bf16(W[k][n])  — transpose + convert weight (512x256)
// ---------------------------------------------------------------------------
__global__ __launch_bounds__(256) void wt_kernel(const float* __restrict__ W,
                                                 short* __restrict__ Wt) {
    int idx = blockIdx.x * 256 + threadIdx.x;
    if (idx < IN_F * OUT_F) {
        int n = idx >> 9;          // /512
        int k = idx & 511;
        Wt[idx] = bf16rne(W[(size_t)k * OUT_F + n]);
    }
}

// ---------------------------------------------------------------------------
// Kernel 1: support(bf16) = features @ weight via bf16 MFMA.
// BM=64, BN=256 (full N -> A read once), BK=32. 4 waves, wave owns 64 cols.
// ---------------------------------------------------------------------------
#define ASTRIDE 40
#define BSTRIDE 40

__global__ __launch_bounds__(256) void gemm_mfma_kernel(const float* __restrict__ A,
                                                        const short* __restrict__ Wt,
                                                        unsigned short* __restrict__ Cb) {
    __shared__ short As[64 * ASTRIDE];
    __shared__ short Bs[256 * BSTRIDE];

    const int tid  = threadIdx.x;
    const int wave = tid >> 6;
    const int lane = tid & 63;
    const int m0   = blockIdx.x * 64;
    const int n0w  = wave * 64;

    const int quad = lane >> 4;
    const int l16  = lane & 15;

    const int ar = tid >> 2;
    const int aq = tid & 3;

    f32x4 zero4 = {0.f, 0.f, 0.f, 0.f};
    f32x4 acc[4][4];
#pragma unroll
    for (int i = 0; i < 4; ++i)
#pragma unroll
        for (int j = 0; j < 4; ++j) acc[i][j] = zero4;

    for (int k0 = 0; k0 < IN_F; k0 += 32) {
        {
            const int gm = m0 + ar;
            float4 v0 = make_float4(0.f, 0.f, 0.f, 0.f);
            float4 v1 = v0;
            if (gm < N_NODES) {
                const float* p = A + (size_t)gm * IN_F + k0 + aq * 8;
                v0 = *(const float4*)p;
                v1 = *(const float4*)(p + 4);
            }
            bf16x8 b;
            b[0] = bf16rne(v0.x); b[1] = bf16rne(v0.y);
            b[2] = bf16rne(v0.z); b[3] = bf16rne(v0.w);
            b[4] = bf16rne(v1.x); b[5] = bf16rne(v1.y);
            b[6] = bf16rne(v1.z); b[7] = bf16rne(v1.w);
            *(bf16x8*)&As[ar * ASTRIDE + aq * 8] = b;
        }
        {
            const short* src = Wt + (size_t)tid * IN_F + k0;
            bf16x8 w0 = *(const bf16x8*)(src + 0);
            bf16x8 w1 = *(const bf16x8*)(src + 8);
            bf16x8 w2 = *(const bf16x8*)(src + 16);
            bf16x8 w3 = *(const bf16x8*)(src + 24);
            short* dst = &Bs[tid * BSTRIDE];
            *(bf16x8*)(dst + 0)  = w0;
            *(bf16x8*)(dst + 8)  = w1;
            *(bf16x8*)(dst + 16) = w2;
            *(bf16x8*)(dst + 24) = w3;
        }
        __syncthreads();

        bf16x8 af[4], bf[4];
#pragma unroll
        for (int mt = 0; mt < 4; ++mt)
            af[mt] = *(const bf16x8*)&As[(mt * 16 + l16) * ASTRIDE + quad * 8];
#pragma unroll
        for (int nt = 0; nt < 4; ++nt)
            bf[nt] = *(const bf16x8*)&Bs[(n0w + nt * 16 + l16) * BSTRIDE + quad * 8];

#pragma unroll
        for (int mt = 0; mt < 4; ++mt)
#pragma unroll
            for (int nt = 0; nt < 4; ++nt)
                acc[mt][nt] = __builtin_amdgcn_mfma_f32_16x16x32_bf16(
                    af[mt], bf[nt], acc[mt][nt], 0, 0, 0);
        __syncthreads();
    }

#pragma unroll
    for (int mt = 0; mt < 4; ++mt) {
        const int rbase = m0 + mt * 16 + quad * 4;
#pragma unroll
        for (int i = 0; i < 4; ++i) {
            const int row = rbase + i;
            if (row < N_NODES) {
#pragma unroll
                for (int nt = 0; nt < 4; ++nt)
                    Cb[(size_t)row * OUT_F + n0w + nt * 16 + l16] =
                        (unsigned short)bf16rne(acc[mt][nt][i]);
            }
        }
    }
}

// ---------------------------------------------------------------------------
// Two-pass edge sort (391 buckets x 128 rows).
// Pass A: coarse bin by row>>7, LDS-staged for contiguous bucket runs.
//         binned entry: x = (row&127)<<16 | col, y = fp32 val bits.
// Pass B: per-bucket counting sort over 128 local rows; emits global excl and
//         packed 4B edge records: (col<<16) | bf16(val).
// ---------------------------------------------------------------------------
__global__ __launch_bounds__(256) void zero_bins_kernel(int* __restrict__ binCounts) {
    int i = blockIdx.x * 256 + threadIdx.x;
    if (i < NBINS) binCounts[i] = 0;
}

__global__ __launch_bounds__(256) void histA_kernel(const int* __restrict__ rows,
                                                    int* __restrict__ binCounts) {
    __shared__ int lh[NBINS];
    const int tid = threadIdx.x;
    for (int i = tid; i < NBINS; i += 256) lh[i] = 0;
    __syncthreads();
    for (int i = blockIdx.x * 256 + tid; i < N_EDGES; i += gridDim.x * 256)
        atomicAdd(&lh[rows[i] >> 7], 1);
    __syncthreads();
    for (int i = tid; i < NBINS; i += 256)
        if (lh[i]) atomicAdd(&binCounts[i], lh[i]);
}

// exclusive scan of 391 bin counts (pair-scan, 512 padded, 256 threads)
__global__ __launch_bounds__(256) void scanA_kernel(const int* __restrict__ binCounts,
                                                    int* __restrict__ binStart,
                                                    int* __restrict__ gcursor) {
    __shared__ int stmp[256];
    const int tid = threadIdx.x;
    const int i0 = 2 * tid, i1 = 2 * tid + 1;
    const int a0 = (i0 < NBINS) ? binCounts[i0] : 0;
    const int a1 = (i1 < NBINS) ? binCounts[i1] : 0;
    const int pair = a0 + a1;
    stmp[tid] = pair;
    for (int off = 1; off < 256; off <<= 1) {
        __syncthreads();
        int t = (tid >= off) ? stmp[tid - off] : 0;
        __syncthreads();
        stmp[tid] += t;
    }
    __syncthreads();
    const int pexcl = stmp[tid] - pair;
    if (i0 < NBINS) { binStart[i0] = pexcl;      gcursor[i0] = pexcl; }
    if (i1 < NBINS) { binStart[i1] = pexcl + a0; gcursor[i1] = pexcl + a0; }
}

__global__ __launch_bounds__(256) void fillA_kernel(const int* __restrict__ rows,
                                                    const int* __restrict__ cols,
                                                    const float* __restrict__ vals,
                                                    int* __restrict__ gcursor,
                                                    int2* __restrict__ binned) {
    __shared__ int lhist[NBINS];
    __shared__ int lexcl[NBINS];
    __shared__ int gbase[NBINS];
    __shared__ int stmp[256];
    __shared__ int2 lstage[BATCH];
    __shared__ unsigned short sbucket[BATCH];

    const int tid   = threadIdx.x;
    const int start = blockIdx.x * BATCH;
    const int count = min(BATCH, N_EDGES - start);

    for (int i = tid; i < NBINS; i += 256) lhist[i] = 0;
    __syncthreads();

    int myrow[8], myrank[8];
#pragma unroll
    for (int j = 0; j < 8; ++j) {
        const int s = j * 256 + tid;
        if (s < count) {
            const int r = rows[start + s];
            myrow[j]  = r;
            myrank[j] = atomicAdd(&lhist[r >> 7], 1);
        }
    }
    __syncthreads();

    // pair-scan of lhist (391 -> 512 padded) + reserve global space per bucket
    {
        const int i0 = 2 * tid, i1 = 2 * tid + 1;
        const int a0 = (i0 < NBINS) ? lhist[i0] : 0;
        const int a1 = (i1 < NBINS) ? lhist[i1] : 0;
        const int pair = a0 + a1;
        stmp[tid] = pair;
        for (int off = 1; off < 256; off <<= 1) {
            __syncthreads();
            int t = (tid >= off) ? stmp[tid - off] : 0;
            __syncthreads();
            stmp[tid] += t;
        }
        __syncthreads();
        const int pexcl = stmp[tid] - pair;
        if (i0 < NBINS) {
            lexcl[i0] = pexcl;
            gbase[i0] = a0 ? atomicAdd(&gcursor[i0], a0) : 0;
        }
        if (i1 < NBINS) {
            lexcl[i1] = pexcl + a0;
            gbase[i1] = a1 ? atomicAdd(&gcursor[i1], a1) : 0;
        }
    }
    __syncthreads();

    // stage into LDS ordered by bucket
#pragma unroll
    for (int j = 0; j < 8; ++j) {
        const int s = j * 256 + tid;
        if (s < count) {
            const int r   = myrow[j];
            const int b   = r >> 7;
            const int pos = lexcl[b] + myrank[j];
            lstage[pos]  = make_int2(((r & 127) << 16) | cols[start + s],
                                     __float_as_int(vals[start + s]));
            sbucket[pos] = (unsigned short)b;
        }
    }
    __syncthreads();

    // write out: bucket runs contiguous
#pragma unroll
    for (int j = 0; j < 8; ++j) {
        const int s = j * 256 + tid;
        if (s < count) {
            const int b = sbucket[s];
            binned[gbase[b] + (s - lexcl[b])] = lstage[s];
        }
    }
}

__global__ __launch_bounds__(256) void sortB_kernel(const int2* __restrict__ binned,
                                                    const int* __restrict__ binStart,
                                                    const int* __restrict__ binCounts,
                                                    int* __restrict__ excl,
                                                    unsigned int* __restrict__ ecv) {
    __shared__ int lhist[BROWS];
    __shared__ int lcur[BROWS];

    const int tid  = threadIdx.x;
    const int b    = blockIdx.x;
    const int base = binStart[b];
    const int cnt  = binCounts[b];

    if (tid < BROWS) lhist[tid] = 0;
    __syncthreads();

    for (int i = tid; i < cnt; i += 256)
        atomicAdd(&lhist[binned[base + i].x >> 16], 1);
    __syncthreads();

    // scan 128 with first 128 threads (Hillis-Steele in lcur as temp)
    if (tid < BROWS) lcur[tid] = lhist[tid];
    for (int off = 1; off < BROWS; off <<= 1) {
        __syncthreads();
        int t = (tid >= off && tid < BROWS) ? lcur[tid - off] : 0;
        __syncthreads();
        if (tid < BROWS) lcur[tid] += t;
    }
    __syncthreads();
    if (tid < BROWS) {
        const int pexcl = lcur[tid] - lhist[tid];
        const int row   = b * BROWS + tid;
        lcur[tid] = pexcl;
        if (row < N_NODES) excl[row] = base + pexcl;
    }
    __syncthreads();

    for (int i = tid; i < cnt; i += 256) {
        const int2 e  = binned[base + i];
        const int rl  = e.x >> 16;
        const int col = e.x & 0xFFFF;
        const int rank = atomicAdd(&lcur[rl], 1);
        ecv[base + rank] = ((unsigned int)col << 16) |
                           (unsigned short)bf16rne(__int_as_float(e.y));
    }
}

// ---------------------------------------------------------------------------
// Gather: one wave per output row, support bf16 (ushort4/lane), packed 4B
// edge records, 4-edge unroll, fp32 accumulate, fused ReLU.
// ---------------------------------------------------------------------------
__global__ __launch_bounds__(256) void gather_kernel(const ushort4* __restrict__ support,
                                                     const int* __restrict__ excl,
                                                     const unsigned int* __restrict__ ecv,
                                                     float4* __restrict__ out) {
    const int tid  = threadIdx.x;
    const int row  = blockIdx.x * 4 + (tid >> 6);
    const int lane = tid & 63;
    if (row >= N_NODES) return;

    const int start = excl[row];
    const int end   = (row + 1 < N_NODES) ? excl[row + 1] : N_EDGES;

    float4 acc = make_float4(0.f, 0.f, 0.f, 0.f);
    int e = start;
    const int end4 = start + ((end - start) & ~3);
    for (; e < end4; e += 4) {
        const unsigned int p0 = ecv[e];
        const unsigned int p1 = ecv[e + 1];
        const unsigned int p2 = ecv[e + 2];
        const unsigned int p3 = ecv[e + 3];
        const ushort4 s0 = support[(size_t)(p0 >> 16) * 64 + lane];
        const ushort4 s1 = support[(size_t)(p1 >> 16) * 64 + lane];
        const ushort4 s2 = support[(size_t)(p2 >> 16) * 64 + lane];
        const ushort4 s3 = support[(size_t)(p3 >> 16) * 64 + lane];
        const float v0 = b2f((unsigned short)(p0 & 0xFFFF));
        const float v1 = b2f((unsigned short)(p1 & 0xFFFF));
        const float v2 = b2f((unsigned short)(p2 & 0xFFFF));
        const float v3 = b2f((unsigned short)(p3 & 0xFFFF));
        acc.x += v0 * b2f(s0.x); acc.y += v0 * b2f(s0.y);
        acc.z += v0 * b2f(s0.z); acc.w += v0 * b2f(s0.w);
        acc.x += v1 * b2f(s1.x); acc.y += v1 * b2f(s1.y);
        acc.z += v1 * b2f(s1.z); acc.w += v1 * b2f(s1.w);
        acc.x += v2 * b2f(s2.x); acc.y += v2 * b2f(s2.y);
        acc.z += v2 * b2f(s2.z); acc.w += v2 * b2f(s2.w);
        acc.x += v3 * b2f(s3.x); acc.y += v3 * b2f(s3.y);
        acc.z += v3 * b2f(s3.z); acc.w += v3 * b2f(s3.w);
    }
    for (; e < end; ++e) {
        const unsigned int p0 = ecv[e];
        const ushort4 s0 = support[(size_t)(p0 >> 16) * 64 + lane];
        const float v0 = b2f((unsigned short)(p0 & 0xFFFF));
        acc.x += v0 * b2f(s0.x); acc.y += v0 * b2f(s0.y);
        acc.z += v0 * b2f(s0.z); acc.w += v0 * b2f(s0.w);
    }

    acc.x = fmaxf(acc.x, 0.f);
    acc.y = fmaxf(acc.y, 0.f);
    acc.z = fmaxf(acc.z, 0.f);
    acc.w = fmaxf(acc.w, 0.f);
    out[(size_t)row * 64 + lane] = acc;
}

extern "C" void kernel_launch(void* const* d_in, const int* in_sizes, int n_in,
                              void* d_out, int out_size, void* d_ws, size_t ws_size,
                              hipStream_t stream) {
    const float* features  = (const float*)d_in[0];   // [50000, 512]
    const float* weight    = (const float*)d_in[1];   // [512, 256]
    const float* edge_vals = (const float*)d_in[2];   // [1.6M]
    const int*   edge_rows = (const int*)d_in[3];
    const int*   edge_cols = (const int*)d_in[4];
    float* out = (float*)d_out;                       // [50000, 256]

    // workspace layout (8B-aligned chunks first)
    unsigned short* support_bf = (unsigned short*)d_ws;                 // 25.6 MB
    int2*  binned    = (int2*)(support_bf + (size_t)N_NODES * OUT_F);   // 12.8 MB
    unsigned int* ecv = (unsigned int*)(binned + N_EDGES);              // 6.4 MB
    int*   excl      = (int*)(ecv + N_EDGES);                           // 50000
    int*   binCounts = excl + N_NODES;                                  // 512
    int*   binStart  = binCounts + 512;                                 // 512
    int*   gcursor   = binStart + 512;                                  // 512
    short* Wt        = (short*)(gcursor + 512);                         // 131072 bf16

    // 1) weight transpose + bf16 convert
    wt_kernel<<<(IN_F * OUT_F + 255) / 256, 256, 0, stream>>>(weight, Wt);

    // 2) MFMA GEMM: support(bf16) = features @ weight
    gemm_mfma_kernel<<<(N_NODES + 63) / 64, 256, 0, stream>>>(features, Wt, support_bf);

    // 3) two-pass edge sort
    zero_bins_kernel<<<2, 256, 0, stream>>>(binCounts);
    histA_kernel<<<256, 256, 0, stream>>>(edge_rows, binCounts);
    scanA_kernel<<<1, 256, 0, stream>>>(binCounts, binStart, gcursor);
    fillA_kernel<<<NBATCHES, 256, 0, stream>>>(edge_rows, edge_cols, edge_vals,
                                               gcursor, binned);
    sortB_kernel<<<NBINS, 256, 0, stream>>>(binned, binStart, binCounts, excl, ecv);

    // 4) gather + fused ReLU (one wave per row, no atomics)
    gather_kernel<<<(N_NODES + 3) / 4, 256, 0, stream>>>(
        (const ushort4*)support_bf, excl, ecv, (float4*)out);
}